// Round 4
// baseline (177.666 us; speedup 1.0000x reference)
//
#include <hip/hip_runtime.h>

#define CT 256
#define KDIM 2304
#define CSZ2 9216        // one col buffer in shorts: 4 sp x 9 tap x 32 nn x 8 ch (k-major, nn^sp swizzled)

typedef unsigned short u16;
typedef _Float16 h2 __attribute__((ext_vector_type(2)));
typedef _Float16 h8 __attribute__((ext_vector_type(8)));
typedef __attribute__((ext_vector_type(4))) float f32x4;

__device__ __forceinline__ unsigned pkh(float a, float b) {   // two f32 -> packed f16 (RTE)
    h2 r; r[0] = (_Float16)a; r[1] = (_Float16)b;
    return __builtin_bit_cast(unsigned, r);
}

// Fused prep: blocks [0,2048) = x -> xi (f16 interleaved-8); [2048,2336) = W -> pw (f16).
__global__ __launch_bounds__(256) void k_prep(const float* __restrict__ x, uint4* __restrict__ xi,
                                              const float* __restrict__ wgt, uint4* __restrict__ pw)
{
    if (blockIdx.x < 2048) {
        int u = blockIdx.x * 256 + threadIdx.x;        // [0, 524288)
        int bcg = u >> 12, p = u & 4095;
        const float* xp = x + (((size_t)bcg) << 15) + p;
        unsigned r[4];
#pragma unroll
        for (int i = 0; i < 4; ++i)
            r[i] = pkh(xp[(size_t)(2 * i) << 12], xp[(size_t)(2 * i + 1) << 12]);
        uint4 o; o.x = r[0]; o.y = r[1]; o.z = r[2]; o.w = r[3];
        xi[u] = o;
    } else {
        int u = (blockIdx.x - 2048) * 256 + threadIdx.x;   // [0, 73728)
        int kc = u >> 10, rm = u & 1023;
        int m = rm >> 2, j = rm & 3;
        int round = kc / 9, tap = kc - round * 9;
        const float* src = wgt + (size_t)m * KDIM + tap;
        int c0 = round * 32 + j * 8;
        unsigned q[4];
#pragma unroll
        for (int i = 0; i < 4; ++i)
            q[i] = pkh(src[(size_t)(c0 + 2 * i) * 9], src[(size_t)(c0 + 2 * i + 1) * 9]);
        uint4 o; o.x = q[0]; o.y = q[1]; o.z = q[2]; o.w = q[3];
        pw[u] = o;
    }
}

// one gather item in flight: 4 corner 16B loads (direct from L2-resident xi) + weights
struct GB {
    uint4 c00, c01, c10, c11;
    unsigned wx, wy;
};

__device__ __forceinline__ void g_load(int it, int round, size_t xib,
                                       const uint2* s_wt, const int2* s_off,
                                       const uint4* __restrict__ xi, GB& g)
{
    int sp = it / 288;                 // superplane within round (= kb chunk)
    int rem = it - sp * 288;           // tap*32 + nn
    uint2 wp = s_wt[rem];
    int2 of = s_off[rem];
    g.wx = wp.x; g.wy = wp.y;
    const uint4* gp = xi + xib + ((size_t)((round << 2) + sp) << 12);
    g.c00 = gp[of.x & 0xffff];
    g.c01 = gp[(unsigned)of.x >> 16];
    g.c10 = gp[of.y & 0xffff];
    g.c11 = gp[(unsigned)of.y >> 16];
}

__device__ __forceinline__ void g_fin(const GB& g, int it, u16* colb)
{
    h2 w01 = __builtin_bit_cast(h2, g.wx);
    h2 w23 = __builtin_bit_cast(h2, g.wy);
    h2 wxp = (h2){w01[0], w01[0]}, wyp = (h2){w01[1], w01[1]};
    h2 wzp = (h2){w23[0], w23[0]}, wwp = (h2){w23[1], w23[1]};
    const unsigned* a00 = (const unsigned*)&g.c00;
    const unsigned* a01 = (const unsigned*)&g.c01;
    const unsigned* a10 = (const unsigned*)&g.c10;
    const unsigned* a11 = (const unsigned*)&g.c11;
    unsigned o[4];
#pragma unroll
    for (int q = 0; q < 4; ++q) {
        h2 rr = wxp * __builtin_bit_cast(h2, a00[q]) + wyp * __builtin_bit_cast(h2, a01[q])
              + wzp * __builtin_bit_cast(h2, a10[q]) + wwp * __builtin_bit_cast(h2, a11[q]);
        o[q] = __builtin_bit_cast(unsigned, rr);
    }
    // swizzled dst: chunk nn -> nn^sp within each (sp,tap) 32-chunk block (kills the
    // 4-way ds_read bank conflict on the consumer side; bank = ((nn^sp)*4)%32)
    int sp = it / 288;
    int rem = it - sp * 288;
    int dst = (sp * 288 + (rem >> 5) * 32 + ((rem & 31) ^ sp)) * 8;
    uint4 ov; ov.x = o[0]; ov.y = o[1]; ov.z = o[2]; ov.w = o[3];
    *(uint4*)&colb[dst] = ov;
}

// gather one full round (1152 items) with 128 producer threads, 2-deep item pipeline
__device__ __forceinline__ void gather_round(int p, int rnd, size_t xib,
                                             const uint2* s_wt, const int2* s_off,
                                             const uint4* __restrict__ xi, u16* dstbuf)
{
    GB ga, gb;
    g_load(p, rnd, xib, s_wt, s_off, xi, ga);
#pragma unroll
    for (int j = 0; j < 9; j += 2) {
        if (j + 1 < 9) g_load((j + 1) * 128 + p, rnd, xib, s_wt, s_off, xi, gb);
        g_fin(ga, j * 128 + p, dstbuf);
        if (j + 2 < 9) g_load((j + 2) * 128 + p, rnd, xib, s_wt, s_off, xi, ga);
        if (j + 1 < 9) g_fin(gb, (j + 1) * 128 + p, dstbuf);
    }
}

// Wave-specialized: 10 waves = 8 consumers (att + MFMA + GN epilogue) + 2 producers
// (deformable gather from L2-resident xi into double-buffered col). Branches are
// wave-uniform with MATCHED barrier counts (1 + 8 + 1 each). Register sets are
// disjoint per branch (acc/aa live only in consumer code) -> no spills.
// XCD-swizzled blocks: each XCD owns one image b (2MB xi slice stays L2-hot).
__global__ __launch_bounds__(640, 5) void k_main(const uint4* __restrict__ xi, const float* __restrict__ off,
                                                 const uint4* __restrict__ pw, const float* __restrict__ att_w,
                                                 const float* __restrict__ att_b,
                                                 float* __restrict__ outp, float* __restrict__ gnpart)
{
    __shared__ uint2 s_wt[288];                    // bilinear corner weights as 4 x f16
    __shared__ int2 s_off[288];                    // packed corner positions
    __shared__ __align__(16) u16 col[2 * CSZ2];    // double-buffered k-major col, f16
    __shared__ float s_att[32];

    // XCD-aware swizzle: xcd = bid&7 (round-robin dispatch); each XCD gets one image b.
    int bid = blockIdx.x;
    int xcd = bid & 7, idx = bid >> 3;
    int b = xcd >> 1;
    int local = ((xcd & 1) << 6) + idx;           // 0..127 within image
    int h = local >> 1, half = local & 1;
    int lbid = b * 128 + local;                   // logical block id (gnpart layout for k_gn)
    int n0 = half * 32;

    int tid = threadIdx.x;
    int lane = tid & 63, w = tid >> 6;

    // bilinear coords for this block's 32 positions (all 640 threads)
    for (int e = tid; e < 288; e += 640) {
        int kk = e >> 5, wl = e & 31;
        int ww_ = n0 + wl;
        int ky = kk / 3, kx = kk - ky * 3;
        float dy = off[((size_t)(b * 18 + 2 * kk) * 64 + h) * 64 + ww_];
        float dx = off[((size_t)(b * 18 + 2 * kk + 1) * 64 + h) * 64 + ww_];
        float py = (float)(h + ky - 1) + dy;
        float px = (float)(ww_ + kx - 1) + dx;
        float y0f = floorf(py), x0f = floorf(px);
        int y0 = (int)y0f, x0 = (int)x0f;
        float fy = py - y0f, fx = px - x0f;
        float vy0 = (y0 >= 0 && y0 < 64) ? 1.f : 0.f;
        float vy1 = (y0 >= -1 && y0 < 63) ? 1.f : 0.f;
        float vx0 = (x0 >= 0 && x0 < 64) ? 1.f : 0.f;
        float vx1 = (x0 >= -1 && x0 < 63) ? 1.f : 0.f;
        float w0 = (1.f - fy) * (1.f - fx) * vy0 * vx0;
        float w1 = (1.f - fy) * fx * vy0 * vx1;
        float w2 = fy * (1.f - fx) * vy1 * vx0;
        float w3 = fy * fx * vy1 * vx1;
        uint2 wp;
        wp.x = pkh(w0, w1);
        wp.y = pkh(w2, w3);
        int yc0 = min(max(y0, 0), 63), yc1 = min(max(y0 + 1, 0), 63);
        int xc0 = min(max(x0, 0), 63), xc1 = min(max(x0 + 1, 0), 63);
        s_wt[e] = wp;
        s_off[e] = make_int2((yc0 * 64 + xc0) | ((yc0 * 64 + xc1) << 16),
                             (yc1 * 64 + xc0) | ((yc1 * 64 + xc1) << 16));
    }

    size_t xib = (size_t)(b * 32) << 12;           // base of this image's 32 superplanes

    __syncthreads();                               // (#1) s_wt/s_off ready

    if (w < 8) {
        // ================= CONSUMER: attention + MFMA + epilogue =================
        int l15 = lane & 15, kb = lane >> 4;
        int wm = w * 32;
        int nn_a = w * 4 + (lane >> 4);
        int ca = (lane & 15) * 2;                  // round-local channel pair

        float att_acc = 0.f;
        f32x4 acc[2][2];
#pragma unroll
        for (int mt = 0; mt < 2; ++mt)
#pragma unroll
            for (int nt = 0; nt < 2; ++nt) acc[mt][nt] = (f32x4){0.f, 0.f, 0.f, 0.f};

        int pwoff[2];
#pragma unroll
        for (int mt = 0; mt < 2; ++mt) pwoff[mt] = (wm + mt * 16 + l15) * 4 + kb;

        // A-stream prefetch: k-steps 0..2 of round 0 (3-deep rotation, slot = ts % 3)
        uint4 aa[3][2];
#pragma unroll
        for (int ts = 0; ts < 3; ++ts)
#pragma unroll
            for (int mt = 0; mt < 2; ++mt)
                aa[ts][mt] = pw[(size_t)ts * 1024 + pwoff[mt]];

        __syncthreads();                           // (#2) col[0] ready

        for (int r = 0; r < 8; ++r) {
            const u16* cb = col + (r & 1) * CSZ2;  // current buffer (producers fill the other)

            // attention tap-max + dot: this lane covers (nn_a, channels ca,ca+1)
            {
                int spa = ca >> 3, co = ca & 7;
                const u16* base = &cb[spa * 2304 + ((nn_a ^ spa)) * 8 + co];
                float m0 = -1e30f, m1 = -1e30f;
#pragma unroll
                for (int t = 0; t < 9; ++t) {
                    unsigned v = *(const unsigned*)(base + t * 256);
                    h2 vv = __builtin_bit_cast(h2, v);
                    m0 = fmaxf(m0, (float)vv[0]);
                    m1 = fmaxf(m1, (float)vv[1]);
                }
                int cbx = r * 32 + ca;
                att_acc += att_w[cbx] * m0 + att_w[cbx + 1] * m1;
            }

            // MFMA over 9 k-steps; 3-deep rolling A buffer (slot ts%3, refill with ts+3,
            // crossing into round r+1 at ts=6..8). B-reads use the nn^kb swizzle.
#pragma unroll
            for (int ts = 0; ts < 9; ++ts) {
                h8 bf[2];
#pragma unroll
                for (int nt = 0; nt < 2; ++nt)
                    bf[nt] = *(const h8*)&cb[kb * 2304 + ts * 256 + (((nt * 16 + l15) ^ kb)) * 8];
                h8 af[2];
#pragma unroll
                for (int mt = 0; mt < 2; ++mt) af[mt] = __builtin_bit_cast(h8, aa[ts % 3][mt]);
                if (ts + 3 < 9) {
#pragma unroll
                    for (int mt = 0; mt < 2; ++mt)
                        aa[ts % 3][mt] = pw[(size_t)(r * 9 + ts + 3) * 1024 + pwoff[mt]];
                } else if (r < 7) {
#pragma unroll
                    for (int mt = 0; mt < 2; ++mt)
                        aa[ts % 3][mt] = pw[(size_t)((r + 1) * 9 + (ts - 6)) * 1024 + pwoff[mt]];
                }
#pragma unroll
                for (int mt = 0; mt < 2; ++mt)
#pragma unroll
                    for (int nt = 0; nt < 2; ++nt)
                        acc[mt][nt] = __builtin_amdgcn_mfma_f32_16x16x32_f16(af[mt], bf[nt], acc[mt][nt], 0, 0, 0);
            }
            __syncthreads();                       // (#3..#10) round boundary
        }

        // finalize attention: reduce over the 16 lanes sharing nn_a, sigmoid, broadcast
#pragma unroll
        for (int d = 1; d <= 8; d <<= 1) att_acc += __shfl_xor(att_acc, d);
        if ((lane & 15) == 0) s_att[nn_a] = 1.f / (1.f + expf(-(att_acc + att_b[0])));
        __syncthreads();                           // (#11)

        float attn[2];
#pragma unroll
        for (int nt = 0; nt < 2; ++nt) attn[nt] = s_att[nt * 16 + l15];

        // epilogue: scale by att, write out, GN partial sums
#pragma unroll
        for (int mt = 0; mt < 2; ++mt) {
            float s1 = 0.f, s2 = 0.f;
#pragma unroll
            for (int nt = 0; nt < 2; ++nt)
#pragma unroll
                for (int r = 0; r < 4; ++r) {
                    float v = acc[mt][nt][r] * attn[nt];
                    int m = wm + mt * 16 + kb * 4 + r;
                    outp[(((size_t)(b * CT + m)) << 12) + h * 64 + n0 + nt * 16 + l15] = v;
                    s1 += v; s2 += v * v;
                }
#pragma unroll
            for (int d = 1; d <= 16; d <<= 1) {
                s1 += __shfl_xor(s1, d);
                s2 += __shfl_xor(s2, d);
            }
            if ((lane & 31) == 0) {
                int gidx = w * 4 + mt * 2 + (kb >> 1);
                gnpart[lbid * 64 + gidx * 2] = s1;
                gnpart[lbid * 64 + gidx * 2 + 1] = s2;
            }
        }
    } else {
        // ================= PRODUCER: deformable gather into col =================
        int p = tid - 512;                         // [0,128)

        gather_round(p, 0, xib, s_wt, s_off, xi, col);   // round 0 -> col[0]
        __syncthreads();                           // (#2) col[0] ready

        for (int r = 0; r < 8; ++r) {
            if (r < 7)
                gather_round(p, r + 1, xib, s_wt, s_off, xi, col + ((r + 1) & 1) * CSZ2);
            __syncthreads();                       // (#3..#10) round boundary
        }
        __syncthreads();                           // (#11) match consumer's s_att barrier
    }
}

// Fused GroupNorm: one block per (b,g); reduce 128 partial pairs -> stats -> normalize 32768 floats.
__global__ __launch_bounds__(256) void k_gn(const float* __restrict__ gnpart, const float* __restrict__ gamma,
                                            const float* __restrict__ beta, float* __restrict__ outp)
{
    __shared__ float rs1[128], rs2[128];
    __shared__ float s_stat[2];
    int bg = blockIdx.x;               // b = bg>>5, g = bg&31
    int b = bg >> 5, g = bg & 31;
    int tid = threadIdx.x;
    if (tid < 128) {
        int blk = (b * 64 + (tid >> 1)) * 2 + (tid & 1);
        rs1[tid] = gnpart[blk * 64 + g * 2];
        rs2[tid] = gnpart[blk * 64 + g * 2 + 1];
    }
    __syncthreads();
    if (tid < 64) {
        float a = rs1[tid] + rs1[tid + 64];
        float c = rs2[tid] + rs2[tid + 64];
#pragma unroll
        for (int d = 1; d <= 32; d <<= 1) {
            a += __shfl_xor(a, d);
            c += __shfl_xor(c, d);
        }
        if (tid == 0) {
            float mean = a * (1.f / 32768.f);
            float var = c * (1.f / 32768.f) - mean * mean;
            s_stat[0] = mean;
            s_stat[1] = rsqrtf(var + 1e-5f);
        }
    }
    __syncthreads();
    float mean = s_stat[0], rstd = s_stat[1];
    float4* p4 = (float4*)(outp + ((size_t)(b * CT + g * 8) << 12));
    for (int i = tid; i < 8192; i += 256) {
        int c = g * 8 + (i >> 10);
        float ga = gamma[c], be = beta[c];
        float4 v = p4[i];
        float4 r;
        r.x = fmaxf((v.x - mean) * rstd * ga + be, 0.f);
        r.y = fmaxf((v.y - mean) * rstd * ga + be, 0.f);
        r.z = fmaxf((v.z - mean) * rstd * ga + be, 0.f);
        r.w = fmaxf((v.w - mean) * rstd * ga + be, 0.f);
        p4[i] = r;
    }
}

extern "C" void kernel_launch(void* const* d_in, const int* in_sizes, int n_in,
                              void* d_out, int out_size, void* d_ws, size_t ws_size,
                              hipStream_t stream)
{
    const float* x = (const float*)d_in[0];
    const float* off = (const float*)d_in[1];
    const float* wgt = (const float*)d_in[2];
    const float* attw = (const float*)d_in[3];
    const float* attb = (const float*)d_in[4];
    const float* gamma = (const float*)d_in[5];
    const float* beta = (const float*)d_in[6];
    float* outp = (float*)d_out;

    char* ws = (char*)d_ws;
    uint4* xi = (uint4*)ws;                          // 8.39 MB
    uint4* pw = (uint4*)(ws + 8388608);              // 1.18 MB
    float* gnpart = (float*)(ws + 9568256);          // 512*64 f32 = 128 KB

    k_prep<<<dim3(2336), dim3(256), 0, stream>>>(x, xi, wgt, pw);
    k_main<<<dim3(512), dim3(640), 0, stream>>>(xi, off, pw, attw, attb, outp, gnpart);
    k_gn<<<dim3(128), dim3(256), 0, stream>>>(gnpart, gamma, beta, outp);
}

// Round 5
// 145.609 us; speedup vs baseline: 1.2202x; 1.2202x over previous
//
#include <hip/hip_runtime.h>

#define CT 256
#define KDIM 2304
#define COLP 296         // padded col row stride in shorts
#define CCOL (32 * COLP) // one col buffer in shorts
#define XSP 4608         // one Xs plane in shorts: 9 rows x 64 pos x 8 ch

typedef unsigned short u16;
typedef _Float16 h2 __attribute__((ext_vector_type(2)));
typedef _Float16 h8 __attribute__((ext_vector_type(8)));
typedef __attribute__((ext_vector_type(4))) float f32x4;

__device__ __forceinline__ unsigned pkh(float a, float b) {   // two f32 -> packed f16 (RTE)
    h2 r; r[0] = (_Float16)a; r[1] = (_Float16)b;
    return __builtin_bit_cast(unsigned, r);
}

// async global->LDS DMA, 16B per lane; LDS dest must be wave-uniform base + lane*16
__device__ __forceinline__ void gload_lds16(const uint4* g, u16* l) {
    __builtin_amdgcn_global_load_lds((const __attribute__((address_space(1))) void*)g,
                                     (__attribute__((address_space(3))) void*)l, 16, 0, 0);
}

// Fused prep: blocks [0,2048) = x -> xi (f16 interleaved-8); [2048,2336) = W -> pw (f16).
__global__ __launch_bounds__(256) void k_prep(const float* __restrict__ x, uint4* __restrict__ xi,
                                              const float* __restrict__ wgt, uint4* __restrict__ pw)
{
    if (blockIdx.x < 2048) {
        int u = blockIdx.x * 256 + threadIdx.x;        // [0, 524288)
        int bcg = u >> 12, p = u & 4095;
        const float* xp = x + (((size_t)bcg) << 15) + p;
        unsigned r[4];
#pragma unroll
        for (int i = 0; i < 4; ++i)
            r[i] = pkh(xp[(size_t)(2 * i) << 12], xp[(size_t)(2 * i + 1) << 12]);
        uint4 o; o.x = r[0]; o.y = r[1]; o.z = r[2]; o.w = r[3];
        xi[u] = o;
    } else {
        int u = (blockIdx.x - 2048) * 256 + threadIdx.x;   // [0, 73728)
        int kc = u >> 10, rm = u & 1023;
        int m = rm >> 2, j = rm & 3;
        int round = kc / 9, tap = kc - round * 9;
        const float* src = wgt + (size_t)m * KDIM + tap;
        int c0 = round * 32 + j * 8;
        unsigned q[4];
#pragma unroll
        for (int i = 0; i < 4; ++i)
            q[i] = pkh(src[(size_t)(c0 + 2 * i) * 9], src[(size_t)(c0 + 2 * i + 1) * 9]);
        uint4 o; o.x = q[0]; o.y = q[1]; o.z = q[2]; o.w = q[3];
        pw[u] = o;
    }
}

// one gather item: bilinear blend of 8 channels (packed f16), write 16B col entry
__device__ __forceinline__ void gather_one(int it2, int sp, int xsb, size_t gfall,
                                           const uint2* s_wt, const int2* s_off,
                                           const u16* Xs, u16* col,
                                           const uint4* __restrict__ xi, int rbase, int nw)
{
    int tap = it2 >> 5, nn = it2 & 31;
    uint2 wp = s_wt[it2];
    h2 w01 = __builtin_bit_cast(h2, wp.x);
    h2 w23 = __builtin_bit_cast(h2, wp.y);
    h2 wxp = (h2){w01[0], w01[0]}, wyp = (h2){w01[1], w01[1]};
    h2 wzp = (h2){w23[0], w23[0]}, wwp = (h2){w23[1], w23[1]};
    int2 of = s_off[it2];
    int P00 = of.x & 0xffff, P01 = (of.x >> 16) & 0xffff;
    int P10 = of.y & 0xffff, P11 = (of.y >> 16) & 0xffff;
    uint4 c00, c01, c10, c11;
    int Q;
    Q = P00 - rbase;
    if ((unsigned)Q < (unsigned)nw) c00 = *(const uint4*)&Xs[xsb + Q * 8]; else c00 = xi[gfall + P00];
    Q = P01 - rbase;
    if ((unsigned)Q < (unsigned)nw) c01 = *(const uint4*)&Xs[xsb + Q * 8]; else c01 = xi[gfall + P01];
    Q = P10 - rbase;
    if ((unsigned)Q < (unsigned)nw) c10 = *(const uint4*)&Xs[xsb + Q * 8]; else c10 = xi[gfall + P10];
    Q = P11 - rbase;
    if ((unsigned)Q < (unsigned)nw) c11 = *(const uint4*)&Xs[xsb + Q * 8]; else c11 = xi[gfall + P11];
    const unsigned* a00 = (const unsigned*)&c00;
    const unsigned* a01 = (const unsigned*)&c01;
    const unsigned* a10 = (const unsigned*)&c10;
    const unsigned* a11 = (const unsigned*)&c11;
    unsigned o[4];
#pragma unroll
    for (int q = 0; q < 4; ++q) {
        h2 r = wxp * __builtin_bit_cast(h2, a00[q]) + wyp * __builtin_bit_cast(h2, a01[q])
             + wzp * __builtin_bit_cast(h2, a10[q]) + wwp * __builtin_bit_cast(h2, a11[q]);
        o[q] = __builtin_bit_cast(unsigned, r);
    }
    uint4 ov; ov.x = o[0]; ov.y = o[1]; ov.z = o[2]; ov.w = o[3];
    *(uint4*)&col[nn * COLP + tap * 32 + sp * 8] = ov;
}

// Fused: deformable unfold (DMA-staged LDS gather, packed f16) + attention (all-wave) +
// MFMA GEMM (register-pipelined A-stream) + GN partials. r0 structure with:
//  - col DOUBLE-buffered: round-r MFMA (top of stage 2r+2) overlaps gather of round r+1
//  - Xs window +-4 rows (outliers -> global fallback), 4 plane-buffers = 36.9KB
//  - XCD-aware block swizzle (each XCD owns one image's xi slice in its L2)
// LDS 79.5KB -> 2 blocks/CU. Grid 512; 512 threads = 8 waves.
__global__ __launch_bounds__(512, 2) void k_main(const uint4* __restrict__ xi, const float* __restrict__ off,
                                                 const uint4* __restrict__ pw, const float* __restrict__ att_w,
                                                 const float* __restrict__ att_b,
                                                 float* __restrict__ outp, float* __restrict__ gnpart)
{
    __shared__ uint2 s_wt[288];        // bilinear corner weights as 4 x f16
    __shared__ int2 s_off[288];        // packed corner positions
    __shared__ u16 Xs[4 * XSP];        // [buf][cgl] planes: <=9 rows x 64 pos x 8 ch each
    __shared__ u16 col[2 * CCOL];      // DOUBLE-buffered 32 n x 288 k (padded), f16
    __shared__ float s_att[32];

    // XCD swizzle: xcd = bid&7 (round-robin dispatch); each XCD owns one image b.
    int bid = blockIdx.x;
    int xcd = bid & 7, idx = bid >> 3;             // idx in [0,64)
    int b = xcd >> 1;
    int local = ((xcd & 1) << 6) + idx;            // [0,128) within image
    int h = local >> 1, half = local & 1;
    int lbid = b * 128 + local;                    // logical block id (k_gn layout)
    int n0 = half * 32;

    int tid = threadIdx.x;
    int lane = tid & 63, w = tid >> 6;
    int l15 = lane & 15, kb = lane >> 4;
    int wm = w * 32;
    // attention assignment: wave w owns positions 4w..4w+3; lane -> (pos, channel-pair)
    int nn_a = w * 4 + (lane >> 4);
    int ca = (lane & 15) * 2;          // round-local channel pair

    // bilinear coords for this block's 32 positions
    for (int e = tid; e < 288; e += 512) {
        int kk = e >> 5, wl = e & 31;
        int ww_ = n0 + wl;
        int ky = kk / 3, kx = kk - ky * 3;
        float dy = off[((size_t)(b * 18 + 2 * kk) * 64 + h) * 64 + ww_];
        float dx = off[((size_t)(b * 18 + 2 * kk + 1) * 64 + h) * 64 + ww_];
        float py = (float)(h + ky - 1) + dy;
        float px = (float)(ww_ + kx - 1) + dx;
        float y0f = floorf(py), x0f = floorf(px);
        int y0 = (int)y0f, x0 = (int)x0f;
        float fy = py - y0f, fx = px - x0f;
        float vy0 = (y0 >= 0 && y0 < 64) ? 1.f : 0.f;
        float vy1 = (y0 >= -1 && y0 < 63) ? 1.f : 0.f;
        float vx0 = (x0 >= 0 && x0 < 64) ? 1.f : 0.f;
        float vx1 = (x0 >= -1 && x0 < 63) ? 1.f : 0.f;
        float w0 = (1.f - fy) * (1.f - fx) * vy0 * vx0;
        float w1 = (1.f - fy) * fx * vy0 * vx1;
        float w2 = fy * (1.f - fx) * vy1 * vx0;
        float w3 = fy * fx * vy1 * vx1;
        uint2 wp;
        wp.x = pkh(w0, w1);
        wp.y = pkh(w2, w3);
        int yc0 = min(max(y0, 0), 63), yc1 = min(max(y0 + 1, 0), 63);
        int xc0 = min(max(x0, 0), 63), xc1 = min(max(x0 + 1, 0), 63);
        s_wt[e] = wp;
        s_off[e] = make_int2((yc0 * 64 + xc0) | ((yc0 * 64 + xc1) << 16),
                             (yc1 * 64 + xc0) | ((yc1 * 64 + xc1) << 16));
    }

    int r0c = max(0, h - 4), r1c = min(63, h + 4);
    int nrows = r1c - r0c + 1, nw = nrows * 64, rbase = r0c * 64;
    size_t xib = (size_t)(b * 32) << 12;               // base of this image's 32 superplanes

    float att_acc = 0.f;
    f32x4 acc[2][2];
#pragma unroll
    for (int mt = 0; mt < 2; ++mt)
#pragma unroll
        for (int nt = 0; nt < 2; ++nt) acc[mt][nt] = (f32x4){0.f, 0.f, 0.f, 0.f};

    int pwoff[2];
#pragma unroll
    for (int mt = 0; mt < 2; ++mt) pwoff[mt] = (wm + mt * 16 + l15) * 4 + kb;

    // issue DMA for stage 0 into buf 0
#pragma unroll
    for (int cgl = 0; cgl < 2; ++cgl)
        for (int e = tid; e < nw; e += 512)
            gload_lds16(&xi[xib + ((size_t)cgl << 12) + rbase + e], &Xs[(cgl * XSP + e * 8)]);

    for (int stage = 0; stage < 16; ++stage) {
        int buf = stage & 1;
        __syncthreads();               // Xs[buf] DMA drained; col/Xs reuse hazards cleared
        if (stage < 15) {              // DMA next stage into Xs[buf^1], lands during ROUND+gather
            size_t nb = xib + ((size_t)((stage + 1) * 2) << 12) + rbase;
#pragma unroll
            for (int cgl = 0; cgl < 2; ++cgl)
                for (int e = tid; e < nw; e += 512)
                    gload_lds16(&xi[nb + ((size_t)cgl << 12) + e],
                                &Xs[(((buf ^ 1) * 2 + cgl) * XSP + e * 8)]);
        }

        if (stage >= 2 && !(stage & 1)) {
            // ROUND(rr): att + MFMA on col[rr&1], overlapped with gather below (col[(rr+1)&1])
            int rr = (stage >> 1) - 1;
            const u16* cb = col + (rr & 1) * CCOL;

            // A-stream start: preload first 4 k-steps (latency hidden behind att)
            uint4 aa[4][2];
#pragma unroll
            for (int ts = 0; ts < 4; ++ts)
#pragma unroll
                for (int mt = 0; mt < 2; ++mt)
                    aa[ts][mt] = pw[(size_t)(rr * 9 + ts) * 1024 + pwoff[mt]];

            // attention tap-max + dot: all waves; this lane covers (nn_a, channels ca,ca+1)
            {
                int sp = ca >> 3, co = ca & 7;
                const u16* base = &cb[nn_a * COLP + sp * 8 + co];
                float m0 = -1e30f, m1 = -1e30f;
#pragma unroll
                for (int t = 0; t < 9; ++t) {
                    unsigned v = *(const unsigned*)(base + t * 32);
                    h2 vv = __builtin_bit_cast(h2, v);
                    m0 = fmaxf(m0, (float)vv[0]);
                    m1 = fmaxf(m1, (float)vv[1]);
                }
                int cbx = rr * 32 + ca;
                att_acc += att_w[cbx] * m0 + att_w[cbx + 1] * m1;
            }

            // MFMA with rolling 4-deep A buffer
#pragma unroll
            for (int ts = 0; ts < 9; ++ts) {
                h8 bf[2];
#pragma unroll
                for (int nt = 0; nt < 2; ++nt)
                    bf[nt] = *(const h8*)&cb[(nt * 16 + l15) * COLP + ts * 32 + kb * 8];
                h8 af[2];
#pragma unroll
                for (int mt = 0; mt < 2; ++mt) af[mt] = __builtin_bit_cast(h8, aa[ts & 3][mt]);
                if (ts + 4 < 9) {
#pragma unroll
                    for (int mt = 0; mt < 2; ++mt)
                        aa[ts & 3][mt] = pw[(size_t)(rr * 9 + ts + 4) * 1024 + pwoff[mt]];
                }
#pragma unroll
                for (int mt = 0; mt < 2; ++mt)
#pragma unroll
                    for (int nt = 0; nt < 2; ++nt)
                        acc[mt][nt] = __builtin_amdgcn_mfma_f32_16x16x32_f16(af[mt], bf[nt], acc[mt][nt], 0, 0, 0);
            }
        }

        // gather: 576 items = 2 cgs x 9 taps x 32 n -> col[(stage>>1)&1]; tail on wave 7
        {
            u16* cw = col + ((stage >> 1) & 1) * CCOL;
            int it = tid;
            int cgl = (it >= 288) ? 1 : 0;
            gather_one(it - cgl * 288, buf * 2 + cgl, (buf * 2 + cgl) * XSP,
                       xib + ((size_t)(stage * 2 + cgl) << 12), s_wt, s_off, Xs, cw, xi, rbase, nw);
            if (tid >= 448) {
                int it2 = tid + 64;    // [512, 576) -> cgl 1
                gather_one(it2 - 288, buf * 2 + 1, (buf * 2 + 1) * XSP,
                           xib + ((size_t)(stage * 2 + 1) << 12), s_wt, s_off, Xs, cw, xi, rbase, nw);
            }
        }
    }

    // final round (7): col[1] complete after stage 15's gather
    __syncthreads();
    {
        int rr = 7;
        const u16* cb = col + (rr & 1) * CCOL;
        uint4 aa[4][2];
#pragma unroll
        for (int ts = 0; ts < 4; ++ts)
#pragma unroll
            for (int mt = 0; mt < 2; ++mt)
                aa[ts][mt] = pw[(size_t)(rr * 9 + ts) * 1024 + pwoff[mt]];
        {
            int sp = ca >> 3, co = ca & 7;
            const u16* base = &cb[nn_a * COLP + sp * 8 + co];
            float m0 = -1e30f, m1 = -1e30f;
#pragma unroll
            for (int t = 0; t < 9; ++t) {
                unsigned v = *(const unsigned*)(base + t * 32);
                h2 vv = __builtin_bit_cast(h2, v);
                m0 = fmaxf(m0, (float)vv[0]);
                m1 = fmaxf(m1, (float)vv[1]);
            }
            int cbx = rr * 32 + ca;
            att_acc += att_w[cbx] * m0 + att_w[cbx + 1] * m1;
        }
#pragma unroll
        for (int ts = 0; ts < 9; ++ts) {
            h8 bf[2];
#pragma unroll
            for (int nt = 0; nt < 2; ++nt)
                bf[nt] = *(const h8*)&cb[(nt * 16 + l15) * COLP + ts * 32 + kb * 8];
            h8 af[2];
#pragma unroll
            for (int mt = 0; mt < 2; ++mt) af[mt] = __builtin_bit_cast(h8, aa[ts & 3][mt]);
            if (ts + 4 < 9) {
#pragma unroll
                for (int mt = 0; mt < 2; ++mt)
                    aa[ts & 3][mt] = pw[(size_t)(rr * 9 + ts + 4) * 1024 + pwoff[mt]];
            }
#pragma unroll
            for (int mt = 0; mt < 2; ++mt)
#pragma unroll
                for (int nt = 0; nt < 2; ++nt)
                    acc[mt][nt] = __builtin_amdgcn_mfma_f32_16x16x32_f16(af[mt], bf[nt], acc[mt][nt], 0, 0, 0);
        }
    }

    // finalize attention: reduce over the 16 lanes sharing nn_a, sigmoid, broadcast
#pragma unroll
    for (int d = 1; d <= 8; d <<= 1) att_acc += __shfl_xor(att_acc, d);
    if ((lane & 15) == 0) s_att[nn_a] = 1.f / (1.f + expf(-(att_acc + att_b[0])));
    __syncthreads();

    float attn[2];
#pragma unroll
    for (int nt = 0; nt < 2; ++nt) attn[nt] = s_att[nt * 16 + l15];

    // epilogue: scale by att, write out, GN partial sums
#pragma unroll
    for (int mt = 0; mt < 2; ++mt) {
        float s1 = 0.f, s2 = 0.f;
#pragma unroll
        for (int nt = 0; nt < 2; ++nt)
#pragma unroll
            for (int r = 0; r < 4; ++r) {
                float v = acc[mt][nt][r] * attn[nt];
                int m = wm + mt * 16 + kb * 4 + r;
                outp[(((size_t)(b * CT + m)) << 12) + h * 64 + n0 + nt * 16 + l15] = v;
                s1 += v; s2 += v * v;
            }
#pragma unroll
        for (int d = 1; d <= 16; d <<= 1) {
            s1 += __shfl_xor(s1, d);
            s2 += __shfl_xor(s2, d);
        }
        if ((lane & 31) == 0) {
            int gidx = w * 4 + mt * 2 + (kb >> 1);
            gnpart[lbid * 64 + gidx * 2] = s1;
            gnpart[lbid * 64 + gidx * 2 + 1] = s2;
        }
    }
}

// Fused GroupNorm: one block per (b,g); reduce 128 partial pairs -> stats -> normalize 32768 floats.
__global__ __launch_bounds__(256) void k_gn(const float* __restrict__ gnpart, const float* __restrict__ gamma,
                                            const float* __restrict__ beta, float* __restrict__ outp)
{
    __shared__ float rs1[128], rs2[128];
    __shared__ float s_stat[2];
    int bg = blockIdx.x;               // b = bg>>5, g = bg&31
    int b = bg >> 5, g = bg & 31;
    int tid = threadIdx.x;
    if (tid < 128) {
        int blk = (b * 64 + (tid >> 1)) * 2 + (tid & 1);
        rs1[tid] = gnpart[blk * 64 + g * 2];
        rs2[tid] = gnpart[blk * 64 + g * 2 + 1];
    }
    __syncthreads();
    if (tid < 64) {
        float a = rs1[tid] + rs1[tid + 64];
        float c = rs2[tid] + rs2[tid + 64];
#pragma unroll
        for (int d = 1; d <= 32; d <<= 1) {
            a += __shfl_xor(a, d);
            c += __shfl_xor(c, d);
        }
        if (tid == 0) {
            float mean = a * (1.f / 32768.f);
            float var = c * (1.f / 32768.f) - mean * mean;
            s_stat[0] = mean;
            s_stat[1] = rsqrtf(var + 1e-5f);
        }
    }
    __syncthreads();
    float mean = s_stat[0], rstd = s_stat[1];
    float4* p4 = (float4*)(outp + ((size_t)(b * CT + g * 8) << 12));
    for (int i = tid; i < 8192; i += 256) {
        int c = g * 8 + (i >> 10);
        float ga = gamma[c], be = beta[c];
        float4 v = p4[i];
        float4 r;
        r.x = fmaxf((v.x - mean) * rstd * ga + be, 0.f);
        r.y = fmaxf((v.y - mean) * rstd * ga + be, 0.f);
        r.z = fmaxf((v.z - mean) * rstd * ga + be, 0.f);
        r.w = fmaxf((v.w - mean) * rstd * ga + be, 0.f);
        p4[i] = r;
    }
}

extern "C" void kernel_launch(void* const* d_in, const int* in_sizes, int n_in,
                              void* d_out, int out_size, void* d_ws, size_t ws_size,
                              hipStream_t stream)
{
    const float* x = (const float*)d_in[0];
    const float* off = (const float*)d_in[1];
    const float* wgt = (const float*)d_in[2];
    const float* attw = (const float*)d_in[3];
    const float* attb = (const float*)d_in[4];
    const float* gamma = (const float*)d_in[5];
    const float* beta = (const float*)d_in[6];
    float* outp = (float*)d_out;

    char* ws = (char*)d_ws;
    uint4* xi = (uint4*)ws;                          // 8.39 MB
    uint4* pw = (uint4*)(ws + 8388608);              // 1.18 MB
    float* gnpart = (float*)(ws + 9568256);          // 512*64 f32 = 128 KB

    k_prep<<<dim3(2336), dim3(256), 0, stream>>>(x, xi, wgt, pw);
    k_main<<<dim3(512), dim3(512), 0, stream>>>(xi, off, pw, attw, attb, outp, gnpart);
    k_gn<<<dim3(128), dim3(256), 0, stream>>>(gnpart, gamma, beta, outp);
}